// Round 1
// baseline (221.829 us; speedup 1.0000x reference)
//
#include <hip/hip_runtime.h>

#define NBINS 128
#define OUT_DIMS 4

__global__ __launch_bounds__(256) void grid_enc3d_kernel(
    const float* __restrict__ x,
    const float4* __restrict__ grid,   // [128*128*128] float4 cells
    float4* __restrict__ out,          // [N] float4
    int n)
{
    int i = blockIdx.x * blockDim.x + threadIdx.x;
    if (i >= n) return;

    // load coords (3 consecutive floats per thread)
    float px = x[3 * i + 0] * (float)NBINS;
    float py = x[3 * i + 1] * (float)NBINS;
    float pz = x[3 * i + 2] * (float)NBINS;

    // clip to [0, NBINS-1]
    px = fminf(fmaxf(px, 0.0f), (float)(NBINS - 1));
    py = fminf(fmaxf(py, 0.0f), (float)(NBINS - 1));
    pz = fminf(fmaxf(pz, 0.0f), (float)(NBINS - 1));

    int ix0 = (int)floorf(px);
    int iy0 = (int)floorf(py);
    int iz0 = (int)floorf(pz);
    int ix1 = min(ix0 + 1, NBINS - 1);
    int iy1 = min(iy0 + 1, NBINS - 1);
    int iz1 = min(iz0 + 1, NBINS - 1);

    float fx = px - (float)ix0;
    float fy = py - (float)iy0;
    float fz = pz - (float)iz0;

    float wx[2] = {1.0f - fx, fx};
    float wy[2] = {1.0f - fy, fy};
    float wz[2] = {1.0f - fz, fz};
    int bx[2] = {ix0 << 14, ix1 << 14};   // ix * 128*128
    int by[2] = {iy0 << 7,  iy1 << 7};    // iy * 128
    int bz[2] = {iz0,       iz1};

    // issue all 8 gathers up front for MLP
    float4 g[8];
#pragma unroll
    for (int dx = 0; dx < 2; dx++)
#pragma unroll
        for (int dy = 0; dy < 2; dy++)
#pragma unroll
            for (int dz = 0; dz < 2; dz++)
                g[dx * 4 + dy * 2 + dz] = grid[bx[dx] + by[dy] + bz[dz]];

    float4 acc = make_float4(0.0f, 0.0f, 0.0f, 0.0f);
#pragma unroll
    for (int dx = 0; dx < 2; dx++)
#pragma unroll
        for (int dy = 0; dy < 2; dy++)
#pragma unroll
            for (int dz = 0; dz < 2; dz++) {
                float w = wx[dx] * wy[dy] * wz[dz];
                float4 gv = g[dx * 4 + dy * 2 + dz];
                acc.x = fmaf(w, gv.x, acc.x);
                acc.y = fmaf(w, gv.y, acc.y);
                acc.z = fmaf(w, gv.z, acc.z);
                acc.w = fmaf(w, gv.w, acc.w);
            }

    out[i] = acc;
}

extern "C" void kernel_launch(void* const* d_in, const int* in_sizes, int n_in,
                              void* d_out, int out_size, void* d_ws, size_t ws_size,
                              hipStream_t stream) {
    const float* x = (const float*)d_in[0];
    const float4* grid = (const float4*)d_in[1];
    float4* out = (float4*)d_out;
    int n = in_sizes[0] / 3;   // N_POINTS

    int block = 256;
    int grid_dim = (n + block - 1) / block;
    grid_enc3d_kernel<<<grid_dim, block, 0, stream>>>(x, grid, out, n);
}